// Round 6
// baseline (2952.109 us; speedup 1.0000x reference)
//
#include <hip/hip_runtime.h>
#include <cstdint>
#include <cstddef>

// ---------------- problem constants ----------------
#define BB 128
#define NMAP 32
#define NPRIM 144
#define NCAP 4608      // 32*144
#define NCLS 10
#define ODIM 16
#define IDIM 8

// ws layout (float offsets)
#define WS_X1H  0                       // x1 hi bf16 NHWC: [128][20][20][256] ushort
#define WS_X1L  6553600                 // x1 lo bf16
#define WS_BH   13107200                // weights hi bf16: [81][256 oc][256 ic] ushort
#define WS_BL   15761408
#define WS_P    18415616                // conv2 out NHWC: [128*144][256]
#define WS_U    23134208                // squash:   [128][4608][8]
#define WS_V    27852800                // routing v: [128][10][16]
#define WS_H1   27873280                // dec h1: [128][512]
#define WS_H2   27938816                // dec h2: [128][1024]
#define WS_CLS  28069888                // argmax class per b (int), 128
#define WS_UHAT 28070016                // u_hat fp32 [b][c][o][n]: 128*10*16*4608
#define UHAT_ELEMS 94371840ULL
#define WS_TOTAL (28070016ULL + UHAT_ELEMS)

// out layout (floats): [128*10 onehot][128*784 reconst][128*10 v_length]
#define OUT_REC  1280
#define OUT_LEN  101632

typedef __attribute__((ext_vector_type(8))) short short8;
typedef __attribute__((ext_vector_type(4))) float f32x4;

// round-to-nearest-even fp32 -> bf16 bits
static __device__ __forceinline__ ushort f2bf(float f) {
    uint u = __float_as_uint(f);
    u = (u + 0x7FFFu + ((u >> 16) & 1u)) >> 16;
    return (ushort)u;
}
static __device__ __forceinline__ float bf2f(ushort h) {
    return __uint_as_float(((uint)h) << 16);
}

// ---------------- kernels ----------------

// conv1 + bias + relu, emitting NHWC bf16 hi/lo directly.
__global__ __launch_bounds__(256) void k_conv1(const float* __restrict__ img,
                                               const float* __restrict__ w,
                                               const float* __restrict__ bias,
                                               ushort* __restrict__ x1h,
                                               ushort* __restrict__ x1l) {
    __shared__ float simg[252];   // 9 rows x 28 cols
    int bi = blockIdx.x;
    int y = bi % 20;
    int b = bi / 20;
    int oc = threadIdx.x;
    if (threadIdx.x < 252)
        simg[threadIdx.x] = img[(size_t)b * 784 + y * 28 + threadIdx.x];
    __syncthreads();

    float acc[20];
    float bv = bias[oc];
#pragma unroll
    for (int x = 0; x < 20; ++x) acc[x] = bv;
    const float* wp = w + oc * 81;
#pragma unroll
    for (int kh = 0; kh < 9; ++kh) {
        float r[28];
#pragma unroll
        for (int j = 0; j < 28; ++j) r[j] = simg[kh * 28 + j];
#pragma unroll
        for (int kw = 0; kw < 9; ++kw) {
            float wv = wp[kh * 9 + kw];
#pragma unroll
            for (int x = 0; x < 20; ++x)
                acc[x] = fmaf(wv, r[x + kw], acc[x]);
        }
    }
    size_t base = ((size_t)b * 400 + y * 20) * 256 + oc;
#pragma unroll
    for (int x = 0; x < 20; ++x) {
        float v = fmaxf(acc[x], 0.f);
        ushort h = f2bf(v);
        ushort lo = f2bf(v - bf2f(h));
        x1h[base + (size_t)x * 256] = h;
        x1l[base + (size_t)x * 256] = lo;
    }
}

// conv2 weights: c2w [oc][ic][81] fp32 -> bh/bl [t=81][oc][ic] bf16 hi/lo
__global__ __launch_bounds__(256) void k_prep_w(const float* __restrict__ w2,
                                                ushort* __restrict__ bh,
                                                ushort* __restrict__ bl) {
    int id = blockIdx.x * 256 + threadIdx.x;   // 65536 = oc*256 + ic
    const float* src = w2 + (size_t)id * 81;
#pragma unroll 9
    for (int t = 0; t < 81; ++t) {
        float v = src[t];
        ushort h = f2bf(v);
        ushort lo = f2bf(v - bf2f(h));
        bh[(size_t)t * 65536 + id] = h;
        bl[(size_t)t * 65536 + id] = lo;
    }
}

// conv2 implicit GEMM, bf16 hi/lo 3-pass MFMA, NO LDS / NO BARRIERS.
// One wave per block computes a 64x64 tile over full K=648 steps; every lane
// loads its MFMA fragments straight from global (16B each) with a register
// ping-pong prefetch. A-frags L1-shared across the 4 nt-waves of one mt;
// B-frags L2-shared. 1152 waves all resident at launch (no tail).
struct Frags { short8 ah[4], al[4], bh[4], bl[4]; };

static __device__ __forceinline__ void load_frags(
    Frags& f, int ks,
    const ushort* __restrict__ x1h, const ushort* __restrict__ x1l,
    const ushort* __restrict__ wbh, const ushort* __restrict__ wbl,
    const int* aoff, const int* boff) {
    int t = ks >> 3, icc = ks & 7;
    int kh = t / 9, kw = t - kh * 9;
    int ka = (kh * 20 + kw) * 256 + icc * 32;
    int kb = t * 65536 + icc * 32;
#pragma unroll
    for (int i = 0; i < 4; ++i) {
        f.ah[i] = *(const short8*)(x1h + (size_t)(aoff[i] + ka));
        f.al[i] = *(const short8*)(x1l + (size_t)(aoff[i] + ka));
        f.bh[i] = *(const short8*)(wbh + (size_t)(boff[i] + kb));
        f.bl[i] = *(const short8*)(wbl + (size_t)(boff[i] + kb));
    }
}

static __device__ __forceinline__ void do_mfma(f32x4 acc[4][4], const Frags& f) {
#pragma unroll
    for (int mf = 0; mf < 4; ++mf)
#pragma unroll
        for (int nf = 0; nf < 4; ++nf) {
            acc[mf][nf] = __builtin_amdgcn_mfma_f32_16x16x32_bf16(f.ah[mf], f.bh[nf], acc[mf][nf], 0, 0, 0);
            acc[mf][nf] = __builtin_amdgcn_mfma_f32_16x16x32_bf16(f.ah[mf], f.bl[nf], acc[mf][nf], 0, 0, 0);
            acc[mf][nf] = __builtin_amdgcn_mfma_f32_16x16x32_bf16(f.al[mf], f.bh[nf], acc[mf][nf], 0, 0, 0);
        }
}

__global__ __launch_bounds__(64, 2) void k_conv2r(
    const ushort* __restrict__ x1h, const ushort* __restrict__ x1l,
    const ushort* __restrict__ wbh, const ushort* __restrict__ wbl,
    const float* __restrict__ bias, float* __restrict__ p) {
    const int lane = threadIdx.x;
    const int wt = blockIdx.x;          // 1152 = 288 m-tiles x 4 n-tiles
    const int nt = wt & 3;
    const int mt = wt >> 2;
    const int m0 = mt * 64, oc0 = nt * 64;
    const int r = lane & 15, kq = lane >> 4;

    int aoff[4], boff[4];
#pragma unroll
    for (int i = 0; i < 4; ++i) {
        int m = m0 + i * 16 + r;
        int bb = m / 144; int s = m - bb * 144; int oh = s / 12; int ow = s - oh * 12;
        aoff[i] = (bb * 400 + oh * 20 + ow) * 256 + kq * 8;
        boff[i] = (oc0 + i * 16 + r) * 256 + kq * 8;
    }

    f32x4 acc[4][4];
#pragma unroll
    for (int mf = 0; mf < 4; ++mf)
#pragma unroll
        for (int nf = 0; nf < 4; ++nf)
            acc[mf][nf] = (f32x4){0.f, 0.f, 0.f, 0.f};

    Frags fa, fb;
    load_frags(fa, 0, x1h, x1l, wbh, wbl, aoff, boff);
    for (int ks = 0; ks < 648; ks += 2) {
        load_frags(fb, ks + 1, x1h, x1l, wbh, wbl, aoff, boff);
        do_mfma(acc, fa);
        int kn = (ks + 2 < 648) ? ks + 2 : 647;
        load_frags(fa, kn, x1h, x1l, wbh, wbl, aoff, boff);
        do_mfma(acc, fb);
    }

    // epilogue: C/D layout col=lane&15 (n), row=(lane>>4)*4+reg (m); bias fused
#pragma unroll
    for (int nf = 0; nf < 4; ++nf) {
        int oc = oc0 + nf * 16 + r;
        float bv = bias[oc];
#pragma unroll
        for (int mf = 0; mf < 4; ++mf) {
            int mb = m0 + mf * 16 + kq * 4;
#pragma unroll
            for (int reg = 0; reg < 4; ++reg)
                p[(size_t)(mb + reg) * 256 + oc] = acc[mf][nf][reg] + bv;
        }
    }
}

// squash primary caps: p[(b*144+pos)][oc=i*32+m] -> u[b, n=m*144+pos, i]
__global__ __launch_bounds__(256) void k_squash(const float* __restrict__ p,
                                                float* __restrict__ u) {
    int id = blockIdx.x * 256 + threadIdx.x;   // B*4608
    int n = id % NCAP;
    int b = id / NCAP;
    int m = n / NPRIM, pos = n - m * NPRIM;
    const float* pp = p + ((size_t)b * 144 + pos) * 256 + m;
    float pv[8];
    float s2 = 0.f;
#pragma unroll
    for (int i = 0; i < 8; ++i) {
        pv[i] = pp[i * 32];
        s2 = fmaf(pv[i], pv[i], s2);
    }
    float f = (s2 / (1.f + s2)) / sqrtf(s2 + 1e-8f);
    float4 a = make_float4(f * pv[0], f * pv[1], f * pv[2], f * pv[3]);
    float4 c = make_float4(f * pv[4], f * pv[5], f * pv[6], f * pv[7]);
    float4* up = (float4*)(u + (size_t)id * 8);
    up[0] = a;
    up[1] = c;
}

// materialize u_hat[b][c][o][n] = sum_i W[m,p,c,o,i] * u[b,n,i],  n = m*144+p.
__global__ __launch_bounds__(256) void k_uhat(const float* __restrict__ u,
                                              const float* __restrict__ W,
                                              float* __restrict__ uh) {
    int c = blockIdx.x % NCLS;
    int m = blockIdx.x / NCLS;
    int tid = threadIdx.x;

    int p_[9], o_[9];
    float4 wr0[9], wr1[9];
#pragma unroll
    for (int j = 0; j < 9; ++j) {
        int idx = j * 256 + tid;          // 2304 = 16 o x 144 p, p fastest
        int pp = idx % 144, oo = idx / 144;
        p_[j] = pp; o_[j] = oo;
        const float4* wp = (const float4*)(W + (((size_t)(m * 144 + pp)) * 10 + c) * 128 + oo * 8);
        wr0[j] = wp[0]; wr1[j] = wp[1];
    }

    for (int b = 0; b < BB; ++b) {
        const float* ub = u + ((size_t)b * NCAP + m * 144) * 8;
        float* ob = uh + ((size_t)(b * 10 + c) * 16) * (size_t)NCAP + m * 144;
#pragma unroll
        for (int j = 0; j < 9; ++j) {
            const float4* up = (const float4*)(ub + p_[j] * 8);
            float4 u0 = up[0], u1 = up[1];
            float val = wr0[j].x * u0.x + wr0[j].y * u0.y + wr0[j].z * u0.z + wr0[j].w * u0.w +
                        wr1[j].x * u1.x + wr1[j].y * u1.y + wr1[j].z * u1.z + wr1[j].w * u1.w;
            ob[(size_t)o_[j] * NCAP + p_[j]] = val;
        }
    }
}

// routing from materialized u_hat: block = (b, c); coalesced dword streams.
__global__ __launch_bounds__(256) void k_route2(const float* __restrict__ uh,
                                                float* __restrict__ v_out) {
    __shared__ float part[4][17];
    __shared__ float sums[17];
    __shared__ float v_l[16];
    int c = blockIdx.x % NCLS;
    int b = blockIdx.x / NCLS;
    int tid = threadIdx.x;
    int lane = tid & 63, wvi = tid >> 6;
    const float* base = uh + (size_t)(b * 10 + c) * 16 * (size_t)NCAP;

    float bij[18];
#pragma unroll
    for (int j = 0; j < 18; ++j) bij[j] = 0.f;

    for (int iter = 0; iter < 3; ++iter) {
        float sZ = 0.f;
        float sS[16];
#pragma unroll
        for (int o = 0; o < 16; ++o) sS[o] = 0.f;

        for (int j = 0; j < 18; ++j) {
            int n = tid + j * 256;
            float uhv[16];
#pragma unroll
            for (int o = 0; o < 16; ++o) uhv[o] = base[(size_t)o * NCAP + n];
            float e;
            if (iter == 0) {
                e = 1.f;
            } else {
                float agr = 0.f;
#pragma unroll
                for (int o = 0; o < 16; ++o) agr = fmaf(uhv[o], v_l[o], agr);
                bij[j] += agr;
                e = __expf(bij[j]);
            }
            sZ += e;
#pragma unroll
            for (int o = 0; o < 16; ++o) sS[o] = fmaf(e, uhv[o], sS[o]);
        }

        float z = sZ;
#pragma unroll
        for (int d = 32; d >= 1; d >>= 1) z += __shfl_xor(z, d, 64);
        if (lane == 0) part[wvi][0] = z;
#pragma unroll
        for (int o = 0; o < 16; ++o) {
            float s = sS[o];
#pragma unroll
            for (int d = 32; d >= 1; d >>= 1) s += __shfl_xor(s, d, 64);
            if (lane == 0) part[wvi][1 + o] = s;
        }
        __syncthreads();
        if (tid < 17)
            sums[tid] = part[0][tid] + part[1][tid] + part[2][tid] + part[3][tid];
        __syncthreads();
        if (tid == 0) {
            float Z = sums[0];
            float s[16];
            float s2 = 0.f;
#pragma unroll
            for (int o = 0; o < 16; ++o) {
                s[o] = sums[1 + o] / Z;
                s2 = fmaf(s[o], s[o], s2);
            }
            float f = (s2 / (1.f + s2)) / sqrtf(s2 + 1e-8f);
#pragma unroll
            for (int o = 0; o < 16; ++o) v_l[o] = f * s[o];
        }
        __syncthreads();
    }
    if (tid < 16)
        v_out[((size_t)b * NCLS + c) * 16 + tid] = v_l[tid];
}

// fallback routing (R3 2-batch recompute) if ws is too small for u_hat
__global__ __launch_bounds__(256) void k_route(const float* __restrict__ u,
                                               const float* __restrict__ W,
                                               float* __restrict__ v_out) {
    __shared__ float red[256 * 17];
    __shared__ float sums[2 * 17];
    __shared__ float v_sh[2][16];
    int c = blockIdx.x % NCLS;
    int bg = blockIdx.x / NCLS;
    int b0 = bg * 2;
    int tid = threadIdx.x;

    float bij[18][2];
#pragma unroll
    for (int j = 0; j < 18; ++j) { bij[j][0] = 0.f; bij[j][1] = 0.f; }

    for (int iter = 0; iter < 3; ++iter) {
        float sZ[2] = {0.f, 0.f};
        float sS[2][16];
#pragma unroll
        for (int o = 0; o < 16; ++o) { sS[0][o] = 0.f; sS[1][o] = 0.f; }

        for (int j = 0; j < 18; ++j) {
            int n = tid + j * 256;
            const float4* w4 = (const float4*)(W + ((size_t)n * NCLS + c) * 128);
            const float4* up0 = (const float4*)(u + ((size_t)b0 * NCAP + n) * 8);
            const float4* up1 = (const float4*)(u + ((size_t)(b0 + 1) * NCAP + n) * 8);
            float4 a0 = up0[0], a1 = up0[1];
            float4 c0 = up1[0], c1 = up1[1];
            float uh[2][16];
#pragma unroll
            for (int o = 0; o < 16; ++o) {
                float4 wa = w4[2 * o], wb = w4[2 * o + 1];
                uh[0][o] = wa.x * a0.x + wa.y * a0.y + wa.z * a0.z + wa.w * a0.w +
                           wb.x * a1.x + wb.y * a1.y + wb.z * a1.z + wb.w * a1.w;
                uh[1][o] = wa.x * c0.x + wa.y * c0.y + wa.z * c0.z + wa.w * c0.w +
                           wb.x * c1.x + wb.y * c1.y + wb.z * c1.z + wb.w * c1.w;
            }
#pragma unroll
            for (int bb = 0; bb < 2; ++bb) {
                float bn = bij[j][bb];
                if (iter > 0) {
                    float agr = 0.f;
#pragma unroll
                    for (int o = 0; o < 16; ++o) agr = fmaf(uh[bb][o], v_sh[bb][o], agr);
                    bn += agr;
                    bij[j][bb] = bn;
                }
                float e = __expf(bn);
                sZ[bb] += e;
#pragma unroll
                for (int o = 0; o < 16; ++o) sS[bb][o] = fmaf(e, uh[bb][o], sS[bb][o]);
            }
        }

#pragma unroll
        for (int bb = 0; bb < 2; ++bb) {
            __syncthreads();
            red[tid * 17 + 0] = sZ[bb];
#pragma unroll
            for (int o = 0; o < 16; ++o) red[tid * 17 + 1 + o] = sS[bb][o];
            __syncthreads();
            if (tid < 17) {
                float s = 0.f;
                for (int t = 0; t < 256; ++t) s += red[t * 17 + tid];
                sums[bb * 17 + tid] = s;
            }
        }
        __syncthreads();
        if (tid < 2) {
            float Z = sums[tid * 17];
            float s[16];
            float s2 = 0.f;
#pragma unroll
            for (int o = 0; o < 16; ++o) {
                s[o] = sums[tid * 17 + 1 + o] / Z;
                s2 = fmaf(s[o], s[o], s2);
            }
            float f = (s2 / (1.f + s2)) / sqrtf(s2 + 1e-8f);
#pragma unroll
            for (int o = 0; o < 16; ++o) v_sh[tid][o] = f * s[o];
        }
        __syncthreads();
    }
    if (tid < 32) {
        int bb = tid >> 4, o = tid & 15;
        v_out[((size_t)(b0 + bb) * NCLS + c) * 16 + o] = v_sh[bb][o];
    }
}

// head: v_length, argmax, one-hot
__global__ __launch_bounds__(64) void k_head(const float* __restrict__ v,
                                             float* __restrict__ out,
                                             int* __restrict__ cls_ws) {
    __shared__ float len2[NCLS];
    __shared__ int cls_sh;
    int b = blockIdx.x, tid = threadIdx.x;
    if (tid < NCLS) {
        float s2 = 0.f;
#pragma unroll
        for (int o = 0; o < 16; ++o) {
            float t = v[((size_t)b * NCLS + tid) * 16 + o];
            s2 = fmaf(t, t, s2);
        }
        len2[tid] = s2;
        out[OUT_LEN + b * NCLS + tid] = sqrtf(s2);
    }
    __syncthreads();
    if (tid == 0) {
        int best = 0;
        float bv = len2[0];
        for (int c2 = 1; c2 < NCLS; ++c2)
            if (len2[c2] > bv) { bv = len2[c2]; best = c2; }
        cls_sh = best;
        cls_ws[b] = best;
    }
    __syncthreads();
    if (tid < NCLS) out[b * NCLS + tid] = (tid == cls_sh) ? 1.0f : 0.0f;
}

// decoder layer 1
__global__ __launch_bounds__(256) void k_dec1(const float* __restrict__ v,
                                              const int* __restrict__ cls_ws,
                                              const float* __restrict__ w1,
                                              const float* __restrict__ b1,
                                              float* __restrict__ h1) {
    int id = blockIdx.x * 256 + threadIdx.x;  // B*512
    int j = id % 512, b = id / 512;
    int cls = cls_ws[b];
    const float* vp = v + ((size_t)b * NCLS + cls) * 16;
    float acc = b1[j];
#pragma unroll
    for (int o = 0; o < 16; ++o)
        acc = fmaf(vp[o], w1[(size_t)(cls * 16 + o) * 512 + j], acc);
    h1[id] = fmaxf(acc, 0.f);
}

// decoder layer 2
__global__ __launch_bounds__(256) void k_dec2(const float* __restrict__ h1,
                                              const float* __restrict__ w2,
                                              const float* __restrict__ b2,
                                              float* __restrict__ h2) {
    __shared__ float hs[512];
    int bi = blockIdx.x;
    int jc = bi % 4;
    int b = bi / 4;
    int tid = threadIdx.x;
    hs[tid] = h1[b * 512 + tid];
    hs[tid + 256] = h1[b * 512 + tid + 256];
    __syncthreads();
    int j = jc * 256 + tid;
    float acc = b2[j];
#pragma unroll 8
    for (int k = 0; k < 512; ++k)
        acc = fmaf(hs[k], w2[(size_t)k * 1024 + j], acc);
    h2[b * 1024 + j] = fmaxf(acc, 0.f);
}

// decoder layer 3 + sigmoid
__global__ __launch_bounds__(256) void k_dec3(const float* __restrict__ h2,
                                              const float* __restrict__ w3,
                                              const float* __restrict__ b3,
                                              float* __restrict__ out) {
    __shared__ float hs[1024];
    int bi = blockIdx.x;
    int jc = bi % 4;
    int b = bi / 4;
    int tid = threadIdx.x;
#pragma unroll
    for (int t = 0; t < 4; ++t) hs[tid + t * 256] = h2[b * 1024 + tid + t * 256];
    __syncthreads();
    int j = jc * 256 + tid;
    if (j < 784) {
        float acc = b3[j];
#pragma unroll 8
        for (int k = 0; k < 1024; ++k)
            acc = fmaf(hs[k], w3[(size_t)k * 784 + j], acc);
        out[OUT_REC + b * 784 + j] = 1.f / (1.f + __expf(-acc));
    }
}

// ---------------- launcher ----------------
extern "C" void kernel_launch(void* const* d_in, const int* in_sizes, int n_in,
                              void* d_out, int out_size, void* d_ws, size_t ws_size,
                              hipStream_t stream) {
    const float* imgs = (const float*)d_in[0];
    const float* c1w  = (const float*)d_in[1];
    const float* c1b  = (const float*)d_in[2];
    const float* c2w  = (const float*)d_in[3];
    const float* c2b  = (const float*)d_in[4];
    const float* Wd   = (const float*)d_in[5];
    const float* dw1  = (const float*)d_in[6];
    const float* db1  = (const float*)d_in[7];
    const float* dw2  = (const float*)d_in[8];
    const float* db2  = (const float*)d_in[9];
    const float* dw3  = (const float*)d_in[10];
    const float* db3  = (const float*)d_in[11];

    float* out = (float*)d_out;
    float* ws  = (float*)d_ws;
    ushort* x1h = (ushort*)(ws + WS_X1H);
    ushort* x1l = (ushort*)(ws + WS_X1L);
    ushort* wbh = (ushort*)(ws + WS_BH);
    ushort* wbl = (ushort*)(ws + WS_BL);
    float* p    = ws + WS_P;
    float* u    = ws + WS_U;
    float* v    = ws + WS_V;
    float* h1   = ws + WS_H1;
    float* h2   = ws + WS_H2;
    int*   cls  = (int*)(ws + WS_CLS);
    float* uhat = ws + WS_UHAT;
    const bool big_ws = ws_size >= WS_TOTAL * 4ULL;

    k_conv1<<<BB * 20, 256, 0, stream>>>(imgs, c1w, c1b, x1h, x1l);
    k_prep_w<<<256, 256, 0, stream>>>(c2w, wbh, wbl);
    k_conv2r<<<1152, 64, 0, stream>>>(x1h, x1l, wbh, wbl, c2b, p);
    k_squash<<<BB * NCAP / 256, 256, 0, stream>>>(p, u);
    if (big_ws) {
        k_uhat<<<NMAP * NCLS, 256, 0, stream>>>(u, Wd, uhat);
        k_route2<<<BB * NCLS, 256, 0, stream>>>(uhat, v);
    } else {
        k_route<<<(BB / 2) * NCLS, 256, 0, stream>>>(u, Wd, v);
    }
    k_head<<<BB, 64, 0, stream>>>(v, out, cls);
    k_dec1<<<BB * 512 / 256, 256, 0, stream>>>(v, cls, dw1, db1, h1);
    k_dec2<<<BB * 4, 256, 0, stream>>>(h1, dw2, db2, h2);
    k_dec3<<<BB * 4, 256, 0, stream>>>(h2, dw3, db3, out);
}

// Round 7
// 1720.762 us; speedup vs baseline: 1.7156x; 1.7156x over previous
//
#include <hip/hip_runtime.h>
#include <cstdint>
#include <cstddef>

// ---------------- problem constants ----------------
#define BB 128
#define NMAP 32
#define NPRIM 144
#define NCAP 4608      // 32*144
#define NCLS 10
#define ODIM 16
#define IDIM 8

// ws layout (float offsets)
#define WS_X1H  0                       // x1 hi bf16 NHWC: [128][20][20][256] ushort
#define WS_X1L  6553600                 // x1 lo bf16
#define WS_BH   13107200                // weights hi bf16: [81][256 oc][256 ic] ushort
#define WS_BL   15761408
#define WS_P    18415616                // conv2 out NHWC: [128*144][256]
#define WS_U    23134208                // squash:   [128][4608][8]
#define WS_V    27852800                // routing v: [128][10][16]
#define WS_H1   27873280                // dec h1: [128][512]
#define WS_H2   27938816                // dec h2: [128][1024]
#define WS_CLS  28069888                // argmax class per b (int), 128
#define WS_UHAT 28070016                // u_hat fp32 [b][c][o][n]: 128*10*16*4608
#define UHAT_ELEMS 94371840ULL
#define WS_TOTAL (28070016ULL + UHAT_ELEMS)

// out layout (floats): [128*10 onehot][128*784 reconst][128*10 v_length]
#define OUT_REC  1280
#define OUT_LEN  101632

typedef __attribute__((ext_vector_type(8))) short short8;
typedef __attribute__((ext_vector_type(4))) float f32x4;

// round-to-nearest-even fp32 -> bf16 bits
static __device__ __forceinline__ ushort f2bf(float f) {
    uint u = __float_as_uint(f);
    u = (u + 0x7FFFu + ((u >> 16) & 1u)) >> 16;
    return (ushort)u;
}
static __device__ __forceinline__ float bf2f(ushort h) {
    return __uint_as_float(((uint)h) << 16);
}

// ---------------- kernels ----------------

// conv1 + bias + relu, emitting NHWC bf16 hi/lo directly.
__global__ __launch_bounds__(256) void k_conv1(const float* __restrict__ img,
                                               const float* __restrict__ w,
                                               const float* __restrict__ bias,
                                               ushort* __restrict__ x1h,
                                               ushort* __restrict__ x1l) {
    __shared__ float simg[252];   // 9 rows x 28 cols
    int bi = blockIdx.x;
    int y = bi % 20;
    int b = bi / 20;
    int oc = threadIdx.x;
    if (threadIdx.x < 252)
        simg[threadIdx.x] = img[(size_t)b * 784 + y * 28 + threadIdx.x];
    __syncthreads();

    float acc[20];
    float bv = bias[oc];
#pragma unroll
    for (int x = 0; x < 20; ++x) acc[x] = bv;
    const float* wp = w + oc * 81;
#pragma unroll
    for (int kh = 0; kh < 9; ++kh) {
        float r[28];
#pragma unroll
        for (int j = 0; j < 28; ++j) r[j] = simg[kh * 28 + j];
#pragma unroll
        for (int kw = 0; kw < 9; ++kw) {
            float wv = wp[kh * 9 + kw];
#pragma unroll
            for (int x = 0; x < 20; ++x)
                acc[x] = fmaf(wv, r[x + kw], acc[x]);
        }
    }
    size_t base = ((size_t)b * 400 + y * 20) * 256 + oc;
#pragma unroll
    for (int x = 0; x < 20; ++x) {
        float v = fmaxf(acc[x], 0.f);
        ushort h = f2bf(v);
        ushort lo = f2bf(v - bf2f(h));
        x1h[base + (size_t)x * 256] = h;
        x1l[base + (size_t)x * 256] = lo;
    }
}

// conv2 weights: c2w [oc][ic][81] fp32 -> bh/bl [t=81][oc][ic] bf16 hi/lo
__global__ __launch_bounds__(256) void k_prep_w(const float* __restrict__ w2,
                                                ushort* __restrict__ bh,
                                                ushort* __restrict__ bl) {
    int id = blockIdx.x * 256 + threadIdx.x;   // 65536 = oc*256 + ic
    const float* src = w2 + (size_t)id * 81;
#pragma unroll 9
    for (int t = 0; t < 81; ++t) {
        float v = src[t];
        ushort h = f2bf(v);
        ushort lo = f2bf(v - bf2f(h));
        bh[(size_t)t * 65536 + id] = h;
        bl[(size_t)t * 65536 + id] = lo;
    }
}

// ---- conv2 with LDS-resident x1 slab (exploits 81x conv tap reuse) ----
// Block = (b, n-half). Outer: 8 ic32 chunks; stage x1[b,:,:,ic32] hi+lo once
// (pitch-padded), inner: 81 taps; A-frags from LDS (prefetched 1 tap ahead),
// B-frags 16B/lane from global (L2/L3-hot), register ping-pong. 2 barriers/chunk.
// 8 waves: nq = wave&3 picks nf-pair, mh = wave>>2 picks m-frags 0..4 / 5..8.

static __device__ __forceinline__ f32x4 mfma16(short8 a, short8 b, f32x4 c) {
    return __builtin_amdgcn_mfma_f32_16x16x32_bf16(a, b, c, 0, 0, 0);
}

template<int NMF>
static __device__ __forceinline__ void tap_loop(
    f32x4 (&acc)[5][2], const ushort* A_lds, const int* celloff,
    const ushort* __restrict__ wbh, const ushort* __restrict__ wbl,
    int boff0, int boff1, int bicc) {
    short8 ah[2][5], al[2][5], bhr[2][2], blr[2][2];
#pragma unroll
    for (int i = 0; i < NMF; ++i) {
        ah[0][i] = *(const short8*)(A_lds + celloff[i]);
        al[0][i] = *(const short8*)(A_lds + 16000 + celloff[i]);
    }
    bhr[0][0] = *(const short8*)(wbh + bicc + boff0);
    bhr[0][1] = *(const short8*)(wbh + bicc + boff1);
    blr[0][0] = *(const short8*)(wbl + bicc + boff0);
    blr[0][1] = *(const short8*)(wbl + bicc + boff1);

#pragma unroll 2
    for (int t = 0; t < 81; ++t) {
        const int cur = t & 1, nxt = cur ^ 1;
        if (t < 80) {
            int tn = t + 1;
            int kh = tn / 9, kw = tn - kh * 9;
            int tapoff = (kh * 20 + kw) * 40;
            size_t bko = (size_t)tn * 65536 + bicc;
            bhr[nxt][0] = *(const short8*)(wbh + bko + boff0);
            bhr[nxt][1] = *(const short8*)(wbh + bko + boff1);
            blr[nxt][0] = *(const short8*)(wbl + bko + boff0);
            blr[nxt][1] = *(const short8*)(wbl + bko + boff1);
#pragma unroll
            for (int i = 0; i < NMF; ++i) {
                ah[nxt][i] = *(const short8*)(A_lds + tapoff + celloff[i]);
                al[nxt][i] = *(const short8*)(A_lds + 16000 + tapoff + celloff[i]);
            }
        }
        // 3 passes, pass-outermost so dependent MFMAs on the same acc are spaced
#pragma unroll
        for (int i = 0; i < NMF; ++i)
#pragma unroll
            for (int j = 0; j < 2; ++j)
                acc[i][j] = mfma16(ah[cur][i], bhr[cur][j], acc[i][j]);
#pragma unroll
        for (int i = 0; i < NMF; ++i)
#pragma unroll
            for (int j = 0; j < 2; ++j)
                acc[i][j] = mfma16(ah[cur][i], blr[cur][j], acc[i][j]);
#pragma unroll
        for (int i = 0; i < NMF; ++i)
#pragma unroll
            for (int j = 0; j < 2; ++j)
                acc[i][j] = mfma16(al[cur][i], bhr[cur][j], acc[i][j]);
    }
}

template<int MF0, int NMF>
static __device__ __forceinline__ void conv2s_epi(
    const f32x4 (&acc)[5][2], const float* __restrict__ bias,
    float* __restrict__ p, int b, int oc0, int nq, int r, int kq) {
#pragma unroll
    for (int j = 0; j < 2; ++j) {
        int oc = oc0 + (nq * 2 + j) * 16 + r;
        float bv = bias[oc];
#pragma unroll
        for (int i = 0; i < NMF; ++i) {
            int row = b * 144 + (MF0 + i) * 16 + kq * 4;
#pragma unroll
            for (int reg = 0; reg < 4; ++reg)
                p[(size_t)(row + reg) * 256 + oc] = acc[i][j][reg] + bv;
        }
    }
}

__global__ __launch_bounds__(512, 2) void k_conv2s(
    const ushort* __restrict__ x1h, const ushort* __restrict__ x1l,
    const ushort* __restrict__ wbh, const ushort* __restrict__ wbl,
    const float* __restrict__ bias, float* __restrict__ p) {
    __shared__ ushort A_lds[32000];   // [comp 2][cell 400][pitch 40 ushort = 80B]

    const int tid = threadIdx.x;
    const int lane = tid & 63;
    const int wv = tid >> 6;          // 0..7
    const int mh = wv >> 2;           // 0: m-frags 0..4, 1: 5..8 (SIMD-pair balanced)
    const int nq = wv & 3;            // nf pair
    const int b  = blockIdx.x >> 1;
    const int nt = blockIdx.x & 1;
    const int oc0 = nt * 128;
    const int r = lane & 15, kq = lane >> 4;
    const int MF0r = mh ? 5 : 0;

    int celloff[5];
#pragma unroll
    for (int i = 0; i < 5; ++i) {
        int lm = (MF0r + i) * 16 + r;          // mh1 i=4 unused (harmless)
        celloff[i] = ((lm / 12) * 20 + (lm % 12)) * 40 + kq * 8;
    }
    const int boff0 = (oc0 + (nq * 2 + 0) * 16 + r) * 256 + kq * 8;
    const int boff1 = (oc0 + (nq * 2 + 1) * 16 + r) * 256 + kq * 8;

    f32x4 acc[5][2];
#pragma unroll
    for (int i = 0; i < 5; ++i)
#pragma unroll
        for (int j = 0; j < 2; ++j)
            acc[i][j] = (f32x4){0.f, 0.f, 0.f, 0.f};

    for (int icc = 0; icc < 8; ++icc) {
        if (icc) __syncthreads();
        // stage x1[b, all 400 cells, icc*32..+32] hi+lo: 3200 16B chunks
#pragma unroll
        for (int rd = 0; rd < 7; ++rd) {
            int idx = rd * 512 + tid;
            if (idx < 3200) {
                int comp = (idx >= 1600) ? 1 : 0;
                int ci = idx - comp * 1600;
                int cell = ci >> 2, cc = ci & 3;
                const ushort* src = (comp ? x1l : x1h) +
                    ((size_t)b * 400 + cell) * 256 + icc * 32 + cc * 8;
                short8 val = *(const short8*)src;
                *(short8*)(A_lds + comp * 16000 + cell * 40 + cc * 8) = val;
            }
        }
        __syncthreads();
        int bicc = icc * 32;
        if (mh == 0) tap_loop<5>(acc, A_lds, celloff, wbh, wbl, boff0, boff1, bicc);
        else         tap_loop<4>(acc, A_lds, celloff, wbh, wbl, boff0, boff1, bicc);
    }

    if (mh == 0) conv2s_epi<0, 5>(acc, bias, p, b, oc0, nq, r, kq);
    else         conv2s_epi<5, 4>(acc, bias, p, b, oc0, nq, r, kq);
}

// squash primary caps: p[(b*144+pos)][oc=i*32+m] -> u[b, n=m*144+pos, i]
__global__ __launch_bounds__(256) void k_squash(const float* __restrict__ p,
                                                float* __restrict__ u) {
    int id = blockIdx.x * 256 + threadIdx.x;   // B*4608
    int n = id % NCAP;
    int b = id / NCAP;
    int m = n / NPRIM, pos = n - m * NPRIM;
    const float* pp = p + ((size_t)b * 144 + pos) * 256 + m;
    float pv[8];
    float s2 = 0.f;
#pragma unroll
    for (int i = 0; i < 8; ++i) {
        pv[i] = pp[i * 32];
        s2 = fmaf(pv[i], pv[i], s2);
    }
    float f = (s2 / (1.f + s2)) / sqrtf(s2 + 1e-8f);
    float4 a = make_float4(f * pv[0], f * pv[1], f * pv[2], f * pv[3]);
    float4 c = make_float4(f * pv[4], f * pv[5], f * pv[6], f * pv[7]);
    float4* up = (float4*)(u + (size_t)id * 8);
    up[0] = a;
    up[1] = c;
}

// materialize u_hat[b][c][o][n] = sum_i W[m,p,c,o,i] * u[b,n,i],  n = m*144+p.
__global__ __launch_bounds__(256) void k_uhat(const float* __restrict__ u,
                                              const float* __restrict__ W,
                                              float* __restrict__ uh) {
    int c = blockIdx.x % NCLS;
    int m = blockIdx.x / NCLS;
    int tid = threadIdx.x;

    int p_[9], o_[9];
    float4 wr0[9], wr1[9];
#pragma unroll
    for (int j = 0; j < 9; ++j) {
        int idx = j * 256 + tid;          // 2304 = 16 o x 144 p, p fastest
        int pp = idx % 144, oo = idx / 144;
        p_[j] = pp; o_[j] = oo;
        const float4* wp = (const float4*)(W + (((size_t)(m * 144 + pp)) * 10 + c) * 128 + oo * 8);
        wr0[j] = wp[0]; wr1[j] = wp[1];
    }

    for (int b = 0; b < BB; ++b) {
        const float* ub = u + ((size_t)b * NCAP + m * 144) * 8;
        float* ob = uh + ((size_t)(b * 10 + c) * 16) * (size_t)NCAP + m * 144;
#pragma unroll
        for (int j = 0; j < 9; ++j) {
            const float4* up = (const float4*)(ub + p_[j] * 8);
            float4 u0 = up[0], u1 = up[1];
            float val = wr0[j].x * u0.x + wr0[j].y * u0.y + wr0[j].z * u0.z + wr0[j].w * u0.w +
                        wr1[j].x * u1.x + wr1[j].y * u1.y + wr1[j].z * u1.z + wr1[j].w * u1.w;
            ob[(size_t)o_[j] * NCAP + p_[j]] = val;
        }
    }
}

// routing from materialized u_hat: block = (b, c); coalesced dword streams.
__global__ __launch_bounds__(256) void k_route2(const float* __restrict__ uh,
                                                float* __restrict__ v_out) {
    __shared__ float part[4][17];
    __shared__ float sums[17];
    __shared__ float v_l[16];
    int c = blockIdx.x % NCLS;
    int b = blockIdx.x / NCLS;
    int tid = threadIdx.x;
    int lane = tid & 63, wvi = tid >> 6;
    const float* base = uh + (size_t)(b * 10 + c) * 16 * (size_t)NCAP;

    float bij[18];
#pragma unroll
    for (int j = 0; j < 18; ++j) bij[j] = 0.f;

    for (int iter = 0; iter < 3; ++iter) {
        float sZ = 0.f;
        float sS[16];
#pragma unroll
        for (int o = 0; o < 16; ++o) sS[o] = 0.f;

        for (int j = 0; j < 18; ++j) {
            int n = tid + j * 256;
            float uhv[16];
#pragma unroll
            for (int o = 0; o < 16; ++o) uhv[o] = base[(size_t)o * NCAP + n];
            float e;
            if (iter == 0) {
                e = 1.f;
            } else {
                float agr = 0.f;
#pragma unroll
                for (int o = 0; o < 16; ++o) agr = fmaf(uhv[o], v_l[o], agr);
                bij[j] += agr;
                e = __expf(bij[j]);
            }
            sZ += e;
#pragma unroll
            for (int o = 0; o < 16; ++o) sS[o] = fmaf(e, uhv[o], sS[o]);
        }

        float z = sZ;
#pragma unroll
        for (int d = 32; d >= 1; d >>= 1) z += __shfl_xor(z, d, 64);
        if (lane == 0) part[wvi][0] = z;
#pragma unroll
        for (int o = 0; o < 16; ++o) {
            float s = sS[o];
#pragma unroll
            for (int d = 32; d >= 1; d >>= 1) s += __shfl_xor(s, d, 64);
            if (lane == 0) part[wvi][1 + o] = s;
        }
        __syncthreads();
        if (tid < 17)
            sums[tid] = part[0][tid] + part[1][tid] + part[2][tid] + part[3][tid];
        __syncthreads();
        if (tid == 0) {
            float Z = sums[0];
            float s[16];
            float s2 = 0.f;
#pragma unroll
            for (int o = 0; o < 16; ++o) {
                s[o] = sums[1 + o] / Z;
                s2 = fmaf(s[o], s[o], s2);
            }
            float f = (s2 / (1.f + s2)) / sqrtf(s2 + 1e-8f);
#pragma unroll
            for (int o = 0; o < 16; ++o) v_l[o] = f * s[o];
        }
        __syncthreads();
    }
    if (tid < 16)
        v_out[((size_t)b * NCLS + c) * 16 + tid] = v_l[tid];
}

// fallback routing (R3 2-batch recompute) if ws is too small for u_hat
__global__ __launch_bounds__(256) void k_route(const float* __restrict__ u,
                                               const float* __restrict__ W,
                                               float* __restrict__ v_out) {
    __shared__ float red[256 * 17];
    __shared__ float sums[2 * 17];
    __shared__ float v_sh[2][16];
    int c = blockIdx.x % NCLS;
    int bg = blockIdx.x / NCLS;
    int b0 = bg * 2;
    int tid = threadIdx.x;

    float bij[18][2];
#pragma unroll
    for (int j = 0; j < 18; ++j) { bij[j][0] = 0.f; bij[j][1] = 0.f; }

    for (int iter = 0; iter < 3; ++iter) {
        float sZ[2] = {0.f, 0.f};
        float sS[2][16];
#pragma unroll
        for (int o = 0; o < 16; ++o) { sS[0][o] = 0.f; sS[1][o] = 0.f; }

        for (int j = 0; j < 18; ++j) {
            int n = tid + j * 256;
            const float4* w4 = (const float4*)(W + ((size_t)n * NCLS + c) * 128);
            const float4* up0 = (const float4*)(u + ((size_t)b0 * NCAP + n) * 8);
            const float4* up1 = (const float4*)(u + ((size_t)(b0 + 1) * NCAP + n) * 8);
            float4 a0 = up0[0], a1 = up0[1];
            float4 c0 = up1[0], c1 = up1[1];
            float uh[2][16];
#pragma unroll
            for (int o = 0; o < 16; ++o) {
                float4 wa = w4[2 * o], wb = w4[2 * o + 1];
                uh[0][o] = wa.x * a0.x + wa.y * a0.y + wa.z * a0.z + wa.w * a0.w +
                           wb.x * a1.x + wb.y * a1.y + wb.z * a1.z + wb.w * a1.w;
                uh[1][o] = wa.x * c0.x + wa.y * c0.y + wa.z * c0.z + wa.w * c0.w +
                           wb.x * c1.x + wb.y * c1.y + wb.z * c1.z + wb.w * c1.w;
            }
#pragma unroll
            for (int bb = 0; bb < 2; ++bb) {
                float bn = bij[j][bb];
                if (iter > 0) {
                    float agr = 0.f;
#pragma unroll
                    for (int o = 0; o < 16; ++o) agr = fmaf(uh[bb][o], v_sh[bb][o], agr);
                    bn += agr;
                    bij[j][bb] = bn;
                }
                float e = __expf(bn);
                sZ[bb] += e;
#pragma unroll
                for (int o = 0; o < 16; ++o) sS[bb][o] = fmaf(e, uh[bb][o], sS[bb][o]);
            }
        }

#pragma unroll
        for (int bb = 0; bb < 2; ++bb) {
            __syncthreads();
            red[tid * 17 + 0] = sZ[bb];
#pragma unroll
            for (int o = 0; o < 16; ++o) red[tid * 17 + 1 + o] = sS[bb][o];
            __syncthreads();
            if (tid < 17) {
                float s = 0.f;
                for (int t = 0; t < 256; ++t) s += red[t * 17 + tid];
                sums[bb * 17 + tid] = s;
            }
        }
        __syncthreads();
        if (tid < 2) {
            float Z = sums[tid * 17];
            float s[16];
            float s2 = 0.f;
#pragma unroll
            for (int o = 0; o < 16; ++o) {
                s[o] = sums[tid * 17 + 1 + o] / Z;
                s2 = fmaf(s[o], s[o], s2);
            }
            float f = (s2 / (1.f + s2)) / sqrtf(s2 + 1e-8f);
#pragma unroll
            for (int o = 0; o < 16; ++o) v_sh[tid][o] = f * s[o];
        }
        __syncthreads();
    }
    if (tid < 32) {
        int bb = tid >> 4, o = tid & 15;
        v_out[((size_t)(b0 + bb) * NCLS + c) * 16 + o] = v_sh[bb][o];
    }
}

// head: v_length, argmax, one-hot
__global__ __launch_bounds__(64) void k_head(const float* __restrict__ v,
                                             float* __restrict__ out,
                                             int* __restrict__ cls_ws) {
    __shared__ float len2[NCLS];
    __shared__ int cls_sh;
    int b = blockIdx.x, tid = threadIdx.x;
    if (tid < NCLS) {
        float s2 = 0.f;
#pragma unroll
        for (int o = 0; o < 16; ++o) {
            float t = v[((size_t)b * NCLS + tid) * 16 + o];
            s2 = fmaf(t, t, s2);
        }
        len2[tid] = s2;
        out[OUT_LEN + b * NCLS + tid] = sqrtf(s2);
    }
    __syncthreads();
    if (tid == 0) {
        int best = 0;
        float bv = len2[0];
        for (int c2 = 1; c2 < NCLS; ++c2)
            if (len2[c2] > bv) { bv = len2[c2]; best = c2; }
        cls_sh = best;
        cls_ws[b] = best;
    }
    __syncthreads();
    if (tid < NCLS) out[b * NCLS + tid] = (tid == cls_sh) ? 1.0f : 0.0f;
}

// decoder layer 1
__global__ __launch_bounds__(256) void k_dec1(const float* __restrict__ v,
                                              const int* __restrict__ cls_ws,
                                              const float* __restrict__ w1,
                                              const float* __restrict__ b1,
                                              float* __restrict__ h1) {
    int id = blockIdx.x * 256 + threadIdx.x;  // B*512
    int j = id % 512, b = id / 512;
    int cls = cls_ws[b];
    const float* vp = v + ((size_t)b * NCLS + cls) * 16;
    float acc = b1[j];
#pragma unroll
    for (int o = 0; o < 16; ++o)
        acc = fmaf(vp[o], w1[(size_t)(cls * 16 + o) * 512 + j], acc);
    h1[id] = fmaxf(acc, 0.f);
}

// decoder layer 2
__global__ __launch_bounds__(256) void k_dec2(const float* __restrict__ h1,
                                              const float* __restrict__ w2,
                                              const float* __restrict__ b2,
                                              float* __restrict__ h2) {
    __shared__ float hs[512];
    int bi = blockIdx.x;
    int jc = bi % 4;
    int b = bi / 4;
    int tid = threadIdx.x;
    hs[tid] = h1[b * 512 + tid];
    hs[tid + 256] = h1[b * 512 + tid + 256];
    __syncthreads();
    int j = jc * 256 + tid;
    float acc = b2[j];
#pragma unroll 8
    for (int k = 0; k < 512; ++k)
        acc = fmaf(hs[k], w2[(size_t)k * 1024 + j], acc);
    h2[b * 1024 + j] = fmaxf(acc, 0.f);
}

// decoder layer 3 + sigmoid
__global__ __launch_bounds__(256) void k_dec3(const float* __restrict__ h2,
                                              const float* __restrict__ w3,
                                              const float* __restrict__ b3,
                                              float* __restrict__ out) {
    __shared__ float hs[1024];
    int bi = blockIdx.x;
    int jc = bi % 4;
    int b = bi / 4;
    int tid = threadIdx.x;
#pragma unroll
    for (int t = 0; t < 4; ++t) hs[tid + t * 256] = h2[b * 1024 + tid + t * 256];
    __syncthreads();
    int j = jc * 256 + tid;
    if (j < 784) {
        float acc = b3[j];
#pragma unroll 8
        for (int k = 0; k < 1024; ++k)
            acc = fmaf(hs[k], w3[(size_t)k * 784 + j], acc);
        out[OUT_REC + b * 784 + j] = 1.f / (1.f + __expf(-acc));
    }
}

// ---------------- launcher ----------------
extern "C" void kernel_launch(void* const* d_in, const int* in_sizes, int n_in,
                              void* d_out, int out_size, void* d_ws, size_t ws_size,
                              hipStream_t stream) {
    const float* imgs = (const float*)d_in[0];
    const float* c1w  = (const float*)d_in[1];
    const float* c1b  = (const float*)d_in[2];
    const float* c2w  = (const float*)d_in[3];
    const float* c2b  = (const float*)d_in[4];
    const float* Wd   = (const float*)d_in[5];
    const float* dw1  = (const float*)d_in[6];
    const float* db1  = (const float*)d_in[7];
    const float* dw2  = (const float*)d_in[8];
    const float* db2  = (const float*)d_in[9];
    const float* dw3  = (const float*)d_in[10];
    const float* db3  = (const float*)d_in[11];

    float* out = (float*)d_out;
    float* ws  = (float*)d_ws;
    ushort* x1h = (ushort*)(ws + WS_X1H);
    ushort* x1l = (ushort*)(ws + WS_X1L);
    ushort* wbh = (ushort*)(ws + WS_BH);
    ushort* wbl = (ushort*)(ws + WS_BL);
    float* p    = ws + WS_P;
    float* u    = ws + WS_U;
    float* v    = ws + WS_V;
    float* h1   = ws + WS_H1;
    float* h2   = ws + WS_H2;
    int*   cls  = (int*)(ws + WS_CLS);
    float* uhat = ws + WS_UHAT;
    const bool big_ws = ws_size >= WS_TOTAL * 4ULL;

    k_conv1<<<BB * 20, 256, 0, stream>>>(imgs, c1w, c1b, x1h, x1l);
    k_prep_w<<<256, 256, 0, stream>>>(c2w, wbh, wbl);
    k_conv2s<<<BB * 2, 512, 0, stream>>>(x1h, x1l, wbh, wbl, c2b, p);
    k_squash<<<BB * NCAP / 256, 256, 0, stream>>>(p, u);
    if (big_ws) {
        k_uhat<<<NMAP * NCLS, 256, 0, stream>>>(u, Wd, uhat);
        k_route2<<<BB * NCLS, 256, 0, stream>>>(uhat, v);
    } else {
        k_route<<<(BB / 2) * NCLS, 256, 0, stream>>>(u, Wd, v);
    }
    k_head<<<BB, 64, 0, stream>>>(v, out, cls);
    k_dec1<<<BB * 512 / 256, 256, 0, stream>>>(v, cls, dw1, db1, h1);
    k_dec2<<<BB * 4, 256, 0, stream>>>(h1, dw2, db2, h2);
    k_dec3<<<BB * 4, 256, 0, stream>>>(h2, dw3, db3, out);
}